// Round 2
// baseline (913.099 us; speedup 1.0000x reference)
//
#include <hip/hip_runtime.h>
#include <hip/hip_cooperative_groups.h>

namespace cg = cooperative_groups;

#define DEV __device__ __forceinline__

constexpr int Bc = 2, Tc = 128, Dc = 256, Lc = 8, Hc = 4, DH = 64, Fc = 2048;
constexpr float EPS = 1e-5f, SCALE = 0.125f;  // 1/sqrt(64)
constexpr int NROWS = Bc * Tc * Lc;           // 2048 candidate rows
constexpr int SLAB = NROWS * Dc;              // 524288 floats

// ---- workspace layout (float offsets) ----
constexpr int OFF_K     = 0;                        // B*T*D frame keys
constexpr int OFF_VWOH  = OFF_K + Bc * Tc * Dc;     // B*T*H*D per-head v@Wo partials
constexpr int OFF_QCLS  = OFF_VWOH + Bc * Tc * Hc * Dc;
constexpr int OFF_KCLS  = OFF_QCLS + Dc;
constexpr int OFF_VWOHC = OFF_KCLS + Dc;            // H*D
constexpr int OFF_ENC   = OFF_VWOHC + Hc * Dc;      // B*T*L*D x0, then enc (in-place)
constexpr int OFF_Z     = OFF_ENC + SLAB;           // B*T*L eoc logits
constexpr int OFF_H2    = OFF_Z + NROWS;            // B*T*L*D ln2 rows
constexpr int OFF_U     = OFF_H2 + SLAB;            // G partial-U slabs [G][NROWS][D]

constexpr int RB = 16;                 // rows per FFN task (32KB LDS -> 4 blocks/CU)
constexpr int GSPLIT = 8;              // F-dimension split
constexpr int FS = Fc / GSPLIT;        // 256 f-cols per slice
constexpr int NTASK_FFN = (NROWS / RB) * GSPLIT;  // 1024

DEV int imin(int a, int b) { return a < b ? a : b; }

// ---- shared-memory phase union (32 KB, dominated by FFN tile) ----
struct SMa { float hsm[Dc]; float vsm[Dc]; float red[4]; };
struct SMb { float sv[Hc][Lc + 1]; float aP[Lc][Hc][Lc + 1];
             float redA[Lc][4]; float redB[Lc][4]; };
struct SMc { float h2s[RB][Dc]; float Ts[RB][FS]; };        // 16KB + 16KB
struct SMd { float encs[Lc][Dc]; float zred[2][4][4]; };
struct SMe { int lst[Tc]; int path[Tc]; int cnt; };
union SMu { SMa a; SMb b; SMc c; SMd d; SMe e; };

// block = 256 threads (4 waves).
DEV float blockReduceSum(float v, float* red) {
#pragma unroll
  for (int off = 32; off; off >>= 1) v += __shfl_down(v, off, 64);
  const int lane = threadIdx.x & 63;
  const int w = threadIdx.x >> 6;
  __syncthreads();  // protect red from previous use
  if (lane == 0) red[w] = v;
  __syncthreads();
  return red[0] + red[1] + red[2] + red[3];
}

// ================= phase bodies (shared between coop + fallback) =================

// ---- A: one row r. LN1 + k/v projections + per-head v@Wo; q for CLS row. ----
DEV void prep_task(int r, const float* __restrict__ frames, const float* __restrict__ cls,
                   const float* __restrict__ Wq, const float* __restrict__ bq,
                   const float* __restrict__ Wk, const float* __restrict__ bk,
                   const float* __restrict__ Wv, const float* __restrict__ bv,
                   const float* __restrict__ Wo,
                   const float* __restrict__ g1, const float* __restrict__ b1,
                   float* __restrict__ ws, SMa& s) {
  const int d = threadIdx.x;
  const float x = (r < Bc * Tc) ? frames[r * Dc + d] : cls[d];
  const float sum = blockReduceSum(x, s.red);
  const float m = sum * (1.0f / Dc);
  const float c = x - m;
  const float var = blockReduceSum(c * c, s.red) * (1.0f / Dc);
  s.hsm[d] = c * (1.0f / sqrtf(var + EPS)) * g1[d] + b1[d];
  __syncthreads();

  float ka = bk[d], va = bv[d];
  for (int c2 = 0; c2 < Dc; ++c2) {
    const float h = s.hsm[c2];
    ka = fmaf(h, Wk[c2 * Dc + d], ka);
    va = fmaf(h, Wv[c2 * Dc + d], va);
  }
  if (r < Bc * Tc) ws[OFF_K + r * Dc + d] = ka;
  else             ws[OFF_KCLS + d] = ka;
  s.vsm[d] = va;
  __syncthreads();

#pragma unroll
  for (int hh = 0; hh < Hc; ++hh) {
    float acc = 0.f;
    for (int c2 = 0; c2 < DH; ++c2)
      acc = fmaf(s.vsm[hh * DH + c2], Wo[(hh * DH + c2) * Dc + d], acc);
    if (r < Bc * Tc) ws[OFF_VWOH + r * (Hc * Dc) + hh * Dc + d] = acc;
    else             ws[OFF_VWOHC + hh * Dc + d] = acc;
  }
  if (r == Bc * Tc) {
    float qa = bq[d];
    for (int c2 = 0; c2 < Dc; ++c2) qa = fmaf(s.hsm[c2], Wq[c2 * Dc + d], qa);
    ws[OFF_QCLS + d] = qa;
  }
}

// ---- B: per (b,i): scores + softmax + x0 + LN2 -> h2 slab, x0 slab. ----
DEV void attn_task(int wg, const float* __restrict__ cls, const float* __restrict__ bo,
                   const float* __restrict__ g2, const float* __restrict__ b2,
                   float* __restrict__ ws, SMb& s) {
  const int i = wg & (Tc - 1);
  const int tid = threadIdx.x;
  const int lane = tid & 63;
  const int lmax = imin(Tc - i, Lc);

  {
    const int hh = tid >> 6;
    const float qv = ws[OFF_QCLS + hh * DH + lane];
    for (int j = 0; j <= Lc; ++j) {
      float p = 0.f;
      if (j == 0) p = qv * ws[OFF_KCLS + hh * DH + lane];
      else if (j - 1 < lmax) p = qv * ws[OFF_K + (wg + j - 1) * Dc + hh * DH + lane];
#pragma unroll
      for (int off = 32; off; off >>= 1) p += __shfl_down(p, off, 64);
      if (lane == 0) s.sv[hh][j] = p * SCALE;
    }
  }
  __syncthreads();

  if (tid < Lc * Hc) {
    const int l = (tid >> 2) + 1, h4 = tid & 3;
    if (l <= lmax) {
      float mx = -1e30f;
      for (int j = 0; j <= l; ++j) mx = fmaxf(mx, s.sv[h4][j]);
      float den = 0.f;
      for (int j = 0; j <= l; ++j) den += expf(s.sv[h4][j] - mx);
      const float inv = 1.f / den;
      for (int j = 0; j <= l; ++j) s.aP[l - 1][h4][j] = expf(s.sv[h4][j] - mx) * inv;
    }
  }
  __syncthreads();

  const int d = tid;
  float x0v[Lc];
  {
    const float base = cls[d] + bo[d];
#pragma unroll
    for (int l = 0; l < Lc; ++l) x0v[l] = base;
    for (int j = 0; j <= lmax; ++j) {
      const float* vwp = (j == 0) ? (ws + OFF_VWOHC)
                                  : (ws + OFF_VWOH + (wg + j - 1) * (Hc * Dc));
      for (int h4 = 0; h4 < Hc; ++h4) {
        const float w = vwp[h4 * Dc + d];
        const int lstart = (j == 0) ? 1 : j;
        for (int l = lstart; l <= lmax; ++l) x0v[l - 1] = fmaf(s.aP[l - 1][h4][j], w, x0v[l - 1]);
      }
    }
#pragma unroll
    for (int l = 0; l < Lc; ++l) {
      float p = x0v[l];
#pragma unroll
      for (int off = 32; off; off >>= 1) p += __shfl_down(p, off, 64);
      if (lane == 0) s.redA[l][tid >> 6] = p;
    }
  }
  __syncthreads();

  float mean[Lc];
  {
#pragma unroll
    for (int l = 0; l < Lc; ++l) {
      const float4 s4 = *(const float4*)s.redA[l];
      mean[l] = (s4.x + s4.y + s4.z + s4.w) * (1.f / Dc);
    }
#pragma unroll
    for (int l = 0; l < Lc; ++l) {
      const float cv = x0v[l] - mean[l];
      float p = cv * cv;
#pragma unroll
      for (int off = 32; off; off >>= 1) p += __shfl_down(p, off, 64);
      if (lane == 0) s.redB[l][tid >> 6] = p;
    }
  }
  __syncthreads();

  {
    const float g2d = g2[d], b2d = b2[d];
    for (int l = 1; l <= lmax; ++l) {
      const float4 s4 = *(const float4*)s.redB[l - 1];
      const float var = (s4.x + s4.y + s4.z + s4.w) * (1.f / Dc);
      const float rstd = 1.f / sqrtf(var + EPS);
      ws[OFF_H2 + (wg * Lc + l - 1) * Dc + d] = (x0v[l - 1] - mean[l - 1]) * rstd * g2d + b2d;
      ws[OFF_ENC + (wg * Lc + l - 1) * Dc + d] = x0v[l - 1];
    }
    for (int l = lmax + 1; l <= Lc; ++l) {
      ws[OFF_H2 + (wg * Lc + l - 1) * Dc + d] = 0.f;
      ws[OFF_ENC + (wg * Lc + l - 1) * Dc + d] = 0.f;
    }
  }
}

// ---- C: FFN task = (16 rows) x (256-wide F-slice g). Bit-matches old fma order. ----
DEV void ffn_task(int task, const float* __restrict__ W1, const float* __restrict__ b1f,
                  const float* __restrict__ W2, float* __restrict__ ws, SMc& s) {
  const int rb = task >> 3;
  const int g = task & 7;
  const int r0 = rb * RB;
  const int tid = threadIdx.x;
  const int cg = tid & 63;
  const int rg = tid >> 6;

  // stage h2 rows [r0, r0+16)
#pragma unroll
  for (int it = 0; it < 4; ++it) {
    const int row = it * 4 + rg;
    *(float4*)&s.h2s[row][cg * 4] =
        *(const float4*)&ws[OFF_H2 + (r0 + row) * Dc + cg * 4];
  }
  __syncthreads();

  // ---- GEMM1: T = relu(h2 @ W1_slice + b1f) ----
  const int f0 = g * FS + cg * 4;
  float t[4][4];
  {
    const float4 bb = *(const float4*)&b1f[f0];
#pragma unroll
    for (int r = 0; r < 4; ++r) { t[r][0] = bb.x; t[r][1] = bb.y; t[r][2] = bb.z; t[r][3] = bb.w; }
  }
  {
    const float* Wp = W1 + f0;
    float4 wn[4];
#pragma unroll
    for (int k = 0; k < 4; ++k) wn[k] = *(const float4*)&Wp[k * Fc];
    for (int c = 0; c < Dc; c += 4) {
      float4 wc[4];
#pragma unroll
      for (int k = 0; k < 4; ++k) wc[k] = wn[k];
      {  // branchless prefetch (re-reads last rows on final iter)
        const float* Wn = Wp + imin(c + 4, Dc - 4) * Fc;
#pragma unroll
        for (int k = 0; k < 4; ++k) wn[k] = *(const float4*)&Wn[k * Fc];
      }
#pragma unroll
      for (int r = 0; r < 4; ++r) {
        const float4 h = *(const float4*)&s.h2s[rg * 4 + r][c];
        const float hv[4] = {h.x, h.y, h.z, h.w};
#pragma unroll
        for (int k = 0; k < 4; ++k) {
          t[r][0] = fmaf(hv[k], wc[k].x, t[r][0]);
          t[r][1] = fmaf(hv[k], wc[k].y, t[r][1]);
          t[r][2] = fmaf(hv[k], wc[k].z, t[r][2]);
          t[r][3] = fmaf(hv[k], wc[k].w, t[r][3]);
        }
      }
    }
  }
#pragma unroll
  for (int r = 0; r < 4; ++r) {
    float4 v;
    v.x = fmaxf(t[r][0], 0.f); v.y = fmaxf(t[r][1], 0.f);
    v.z = fmaxf(t[r][2], 0.f); v.w = fmaxf(t[r][3], 0.f);
    *(float4*)&s.Ts[rg * 4 + r][cg * 4] = v;
  }
  __syncthreads();

  // ---- GEMM2: U_partial = T @ W2_slice ----
  float u[4][4];
#pragma unroll
  for (int r = 0; r < 4; ++r) { u[r][0] = 0.f; u[r][1] = 0.f; u[r][2] = 0.f; u[r][3] = 0.f; }
  {
    const float* Wp = W2 + g * FS * Dc + cg * 4;
    float4 wn[4];
#pragma unroll
    for (int k = 0; k < 4; ++k) wn[k] = *(const float4*)&Wp[k * Dc];
    for (int kk = 0; kk < FS; kk += 4) {
      float4 wc[4];
#pragma unroll
      for (int k = 0; k < 4; ++k) wc[k] = wn[k];
      {
        const float* Wn = Wp + imin(kk + 4, FS - 4) * Dc;
#pragma unroll
        for (int k = 0; k < 4; ++k) wn[k] = *(const float4*)&Wn[k * Dc];
      }
#pragma unroll
      for (int r = 0; r < 4; ++r) {
        const float4 a = *(const float4*)&s.Ts[rg * 4 + r][kk];
        const float av[4] = {a.x, a.y, a.z, a.w};
#pragma unroll
        for (int k = 0; k < 4; ++k) {
          u[r][0] = fmaf(av[k], wc[k].x, u[r][0]);
          u[r][1] = fmaf(av[k], wc[k].y, u[r][1]);
          u[r][2] = fmaf(av[k], wc[k].z, u[r][2]);
          u[r][3] = fmaf(av[k], wc[k].w, u[r][3]);
        }
      }
    }
  }
#pragma unroll
  for (int r = 0; r < 4; ++r) {
    float4 v; v.x = u[r][0]; v.y = u[r][1]; v.z = u[r][2]; v.w = u[r][3];
    *(float4*)&ws[OFF_U + (g * NROWS + r0 + rg * 4 + r) * Dc + cg * 4] = v;
  }
}

// ---- D: enc = x0 + sum_g U_g + b2f, then z (256-thread version, bit-exact order) ----
DEV void z_task(int wg, const float* __restrict__ b2f,
                const float* __restrict__ We1, const float* __restrict__ be1,
                const float* __restrict__ We2, const float* __restrict__ be2,
                float* __restrict__ ws, SMd& s) {
  const int tid = threadIdx.x;
  const int wv = tid >> 6, lane = tid & 63;

#pragma unroll
  for (int half = 0; half < 2; ++half) {
    const int r = half * 4 + wv;       // rows 0..7
    const int dg = lane * 4;
    const int row = wg * Lc + r;
    float4 sum = *(const float4*)&ws[OFF_U + (0 * NROWS + row) * Dc + dg];
#pragma unroll
    for (int g = 1; g < GSPLIT; ++g) {
      const float4 p = *(const float4*)&ws[OFF_U + (g * NROWS + row) * Dc + dg];
      sum.x += p.x; sum.y += p.y; sum.z += p.z; sum.w += p.w;
    }
    const float4 x0 = *(const float4*)&ws[OFF_ENC + row * Dc + dg];
    const float4 bb = *(const float4*)&b2f[dg];
    float4 e;
    e.x = (x0.x + sum.x) + bb.x; e.y = (x0.y + sum.y) + bb.y;
    e.z = (x0.z + sum.z) + bb.z; e.w = (x0.w + sum.w) + bb.w;
    *(float4*)&ws[OFF_ENC + row * Dc + dg] = e;
    *(float4*)&s.encs[r][dg] = e;
  }
  __syncthreads();

  const int f = tid;
  const float be1f = be1[f];
  const float w2v = We2[f];
#pragma unroll
  for (int rh = 0; rh < 2; ++rh) {
    float gr[4];
#pragma unroll
    for (int rr = 0; rr < 4; ++rr) gr[rr] = be1f;
    for (int c = 0; c < Dc; c += 4) {
      const float w0 = We1[(c + 0) * Dc + f];
      const float w1 = We1[(c + 1) * Dc + f];
      const float w2 = We1[(c + 2) * Dc + f];
      const float w3 = We1[(c + 3) * Dc + f];
#pragma unroll
      for (int rr = 0; rr < 4; ++rr) {
        const float4 e = *(const float4*)&s.encs[rh * 4 + rr][c];
        gr[rr] = fmaf(e.x, w0, gr[rr]);
        gr[rr] = fmaf(e.y, w1, gr[rr]);
        gr[rr] = fmaf(e.z, w2, gr[rr]);
        gr[rr] = fmaf(e.w, w3, gr[rr]);
      }
    }
#pragma unroll
    for (int rr = 0; rr < 4; ++rr) {
      float p = fmaxf(gr[rr], 0.f) * w2v;
#pragma unroll
      for (int off = 32; off; off >>= 1) p += __shfl_down(p, off, 64);
      if (lane == 0) s.zred[rh][wv][rr] = p;
    }
  }
  __syncthreads();
  if (tid < 8) {
    const int r = tid;
    const int rh = r >> 2, rl = r & 3;
    const float z = ((s.zred[rh][0][rl] + s.zred[rh][1][rl]) + s.zred[rh][2][rl]) +
                    s.zred[rh][3][rl];
    ws[OFF_Z + wg * 8 + r] = z + be2[0];
  }
}

// ---- E: select lstar + sequential walk + emit ----
DEV void emit_task(int b, float* __restrict__ ws, float* __restrict__ out, SMe& s) {
  const int tid = threadIdx.x;
  if (tid < Tc) {
    const int i = tid;
    const int lmax = imin(Tc - i, Lc);
    const float* z = ws + OFF_Z + (b * Tc + i) * Lc;
    int ls = lmax;
    for (int l = 1; l <= lmax; ++l) {
      if (z[l - 1] > 0.f) { ls = l; break; }
    }
    s.lst[tid] = ls;
  }
  __syncthreads();
  if (tid < 64) {
    const int a0 = s.lst[tid], a1 = s.lst[64 + tid];
    int cur = 0, n = 0;
    while (cur < Tc) {
      const int l = (cur < 64) ? __shfl(a0, cur, 64) : __shfl(a1, cur - 64, 64);
      if (tid == 0) s.path[n] = cur * Lc + l - 1;
      ++n;
      cur += l;
    }
    if (tid == 0) s.cnt = n;
  }
  __syncthreads();
  const int c = s.cnt;
  for (int s0 = 0; s0 < Tc; s0 += 8) {
    float v[8];
#pragma unroll
    for (int k = 0; k < 8; ++k) {
      const int st = s0 + k;
      v[k] = (st < c) ? ws[OFF_ENC + (b * Tc * Lc + s.path[st]) * Dc + tid] : 0.f;
    }
#pragma unroll
    for (int k = 0; k < 8; ++k) out[(b * Tc + s0 + k) * Dc + tid] = v[k];
  }
  if (tid == 0) out[Bc * Tc * Dc + b] = (float)c;
}

// ================= single cooperative kernel: all phases =================
__global__ __launch_bounds__(256, 4) void k_all(
    const float* __restrict__ frames, const float* __restrict__ cls,
    const float* __restrict__ Wq, const float* __restrict__ bq,
    const float* __restrict__ Wk, const float* __restrict__ bk,
    const float* __restrict__ Wv, const float* __restrict__ bv,
    const float* __restrict__ Wo, const float* __restrict__ bo,
    const float* __restrict__ g1, const float* __restrict__ b1,
    const float* __restrict__ g2, const float* __restrict__ b2,
    const float* __restrict__ W1, const float* __restrict__ b1f,
    const float* __restrict__ W2, const float* __restrict__ b2f,
    const float* __restrict__ We1, const float* __restrict__ be1,
    const float* __restrict__ We2, const float* __restrict__ be2,
    float* __restrict__ ws, float* __restrict__ out) {
  __shared__ __align__(16) SMu sm;
  cg::grid_group grid = cg::this_grid();
  const int bid = blockIdx.x;
  const int NB = gridDim.x;

  // ---- A ----
  for (int r = bid; r <= Bc * Tc; r += NB)
    prep_task(r, frames, cls, Wq, bq, Wk, bk, Wv, bv, Wo, g1, b1, ws, sm.a);
  grid.sync();

  // ---- B ----
  for (int wg = bid; wg < Bc * Tc; wg += NB)
    attn_task(wg, cls, bo, g2, b2, ws, sm.b);
  grid.sync();

  // ---- C ----
  for (int task = bid; task < NTASK_FFN; task += NB)
    ffn_task(task, W1, b1f, W2, ws, sm.c);
  grid.sync();

  // ---- D ----
  for (int wg = bid; wg < Bc * Tc; wg += NB)
    z_task(wg, b2f, We1, be1, We2, be2, ws, sm.d);
  grid.sync();

  // ---- E ----
  for (int b = bid; b < Bc; b += NB)
    emit_task(b, ws, out, sm.e);
}

// ================= fallback standalone kernels =================
__global__ __launch_bounds__(256) void k_prep(
    const float* __restrict__ frames, const float* __restrict__ cls,
    const float* __restrict__ Wq, const float* __restrict__ bq,
    const float* __restrict__ Wk, const float* __restrict__ bk,
    const float* __restrict__ Wv, const float* __restrict__ bv,
    const float* __restrict__ Wo,
    const float* __restrict__ g1, const float* __restrict__ b1,
    float* __restrict__ ws) {
  __shared__ __align__(16) SMa s;
  prep_task(blockIdx.x, frames, cls, Wq, bq, Wk, bk, Wv, bv, Wo, g1, b1, ws, s);
}

__global__ __launch_bounds__(256) void k_attn(
    const float* __restrict__ cls, const float* __restrict__ bo,
    const float* __restrict__ g2, const float* __restrict__ b2,
    float* __restrict__ ws) {
  __shared__ __align__(16) SMb s;
  attn_task(blockIdx.x, cls, bo, g2, b2, ws, s);
}

__global__ __launch_bounds__(256, 4) void k_ffn16(
    const float* __restrict__ W1, const float* __restrict__ b1f,
    const float* __restrict__ W2, float* __restrict__ ws) {
  __shared__ __align__(16) SMc s;
  ffn_task(blockIdx.x, W1, b1f, W2, ws, s);
}

__global__ __launch_bounds__(256) void k_z(
    const float* __restrict__ b2f,
    const float* __restrict__ We1, const float* __restrict__ be1,
    const float* __restrict__ We2, const float* __restrict__ be2,
    float* __restrict__ ws) {
  __shared__ __align__(16) SMd s;
  z_task(blockIdx.x, b2f, We1, be1, We2, be2, ws, s);
}

__global__ __launch_bounds__(256) void k_emit(float* __restrict__ ws, float* __restrict__ out) {
  __shared__ __align__(16) SMe s;
  emit_task(blockIdx.x, ws, out, s);
}

// ---- tiny-workspace fallback: fully-fused K2 (round-0 kernel, unchanged math) ----
__global__ __launch_bounds__(512) void k_fused(
    const float* __restrict__ cls, const float* __restrict__ bo,
    const float* __restrict__ g2, const float* __restrict__ b2,
    const float* __restrict__ W1, const float* __restrict__ b1f,
    const float* __restrict__ W2, const float* __restrict__ b2f,
    const float* __restrict__ We1, const float* __restrict__ be1,
    const float* __restrict__ We2, const float* __restrict__ be2,
    float* __restrict__ ws) {
  const int wg = blockIdx.x;
  const int i = wg & (Tc - 1);
  const int tid = threadIdx.x;
  const int wv = tid >> 6, lane = tid & 63;
  const int lmax = imin(Tc - i, Lc);

  __shared__ __align__(16) float ts[8][2048];
  __shared__ __align__(16) float h2s[8][256];
  __shared__ __align__(16) float x0s[8][256];
  __shared__ __align__(16) float encs[8][256];
  __shared__ float sv[Hc][Lc + 1];
  __shared__ float aP[Lc][Hc][Lc + 1];
  __shared__ __align__(16) float redA[Lc][4];
  __shared__ __align__(16) float redB[Lc][4];
  __shared__ float zred[8][4];

  if (tid < 256) {
    const int hh = tid >> 6;
    const float qv = ws[OFF_QCLS + hh * DH + lane];
    for (int j = 0; j <= Lc; ++j) {
      float p = 0.f;
      if (j == 0) p = qv * ws[OFF_KCLS + hh * DH + lane];
      else if (j - 1 < lmax) p = qv * ws[OFF_K + (wg + j - 1) * Dc + hh * DH + lane];
#pragma unroll
      for (int off = 32; off; off >>= 1) p += __shfl_down(p, off, 64);
      if (lane == 0) sv[hh][j] = p * SCALE;
    }
  }
  __syncthreads();

  if (tid < Lc * Hc) {
    const int l = (tid >> 2) + 1, h4 = tid & 3;
    if (l <= lmax) {
      float mx = -1e30f;
      for (int j = 0; j <= l; ++j) mx = fmaxf(mx, sv[h4][j]);
      float den = 0.f;
      for (int j = 0; j <= l; ++j) den += expf(sv[h4][j] - mx);
      const float inv = 1.f / den;
      for (int j = 0; j <= l; ++j) aP[l - 1][h4][j] = expf(sv[h4][j] - mx) * inv;
    }
  }
  __syncthreads();

  float x0v[Lc];
  if (tid < 256) {
    const int d = tid;
    const float base = cls[d] + bo[d];
#pragma unroll
    for (int l = 0; l < Lc; ++l) x0v[l] = base;
    for (int j = 0; j <= lmax; ++j) {
      const float* vwp = (j == 0) ? (ws + OFF_VWOHC)
                                  : (ws + OFF_VWOH + (wg + j - 1) * (Hc * Dc));
      for (int h4 = 0; h4 < Hc; ++h4) {
        const float w = vwp[h4 * Dc + d];
        const int lstart = (j == 0) ? 1 : j;
        for (int l = lstart; l <= lmax; ++l) x0v[l - 1] = fmaf(aP[l - 1][h4][j], w, x0v[l - 1]);
      }
    }
#pragma unroll
    for (int l = 0; l < Lc; ++l) {
      float p = x0v[l];
#pragma unroll
      for (int off = 32; off; off >>= 1) p += __shfl_down(p, off, 64);
      if (lane == 0) redA[l][tid >> 6] = p;
    }
  }
  __syncthreads();

  float mean[Lc];
  if (tid < 256) {
#pragma unroll
    for (int l = 0; l < Lc; ++l) {
      const float4 s4 = *(const float4*)redA[l];
      mean[l] = (s4.x + s4.y + s4.z + s4.w) * (1.f / Dc);
    }
#pragma unroll
    for (int l = 0; l < Lc; ++l) {
      const float cv = x0v[l] - mean[l];
      float p = cv * cv;
#pragma unroll
      for (int off = 32; off; off >>= 1) p += __shfl_down(p, off, 64);
      if (lane == 0) redB[l][tid >> 6] = p;
    }
  }
  __syncthreads();

  if (tid < 256) {
    const int d = tid;
    const float g2d = g2[d], b2d = b2[d];
    for (int l = 1; l <= lmax; ++l) {
      const float4 s4 = *(const float4*)redB[l - 1];
      const float var = (s4.x + s4.y + s4.z + s4.w) * (1.f / Dc);
      const float rstd = 1.f / sqrtf(var + EPS);
      h2s[l - 1][d] = (x0v[l - 1] - mean[l - 1]) * rstd * g2d + b2d;
      x0s[l - 1][d] = x0v[l - 1];
    }
    for (int l = lmax + 1; l <= Lc; ++l) {
      h2s[l - 1][d] = 0.f;
      x0s[l - 1][d] = 0.f;
    }
  }
  __syncthreads();

  const int fg = tid * 4;
  float t[8][4];
  {
    const float4 bb = *(const float4*)&b1f[fg];
#pragma unroll
    for (int r = 0; r < 8; ++r) { t[r][0] = bb.x; t[r][1] = bb.y; t[r][2] = bb.z; t[r][3] = bb.w; }
  }
  for (int c = 0; c < Dc; c += 4) {
    float4 w1v[4];
#pragma unroll
    for (int k = 0; k < 4; ++k) w1v[k] = *(const float4*)&W1[(c + k) * Fc + fg];
#pragma unroll
    for (int r = 0; r < 8; ++r) {
      const float4 h = *(const float4*)&h2s[r][c];
      const float hv[4] = {h.x, h.y, h.z, h.w};
#pragma unroll
      for (int k = 0; k < 4; ++k) {
        t[r][0] = fmaf(hv[k], w1v[k].x, t[r][0]);
        t[r][1] = fmaf(hv[k], w1v[k].y, t[r][1]);
        t[r][2] = fmaf(hv[k], w1v[k].z, t[r][2]);
        t[r][3] = fmaf(hv[k], w1v[k].w, t[r][3]);
      }
    }
  }
#pragma unroll
  for (int r = 0; r < 8; ++r) {
    float4 v;
    v.x = fmaxf(t[r][0], 0.f); v.y = fmaxf(t[r][1], 0.f);
    v.z = fmaxf(t[r][2], 0.f); v.w = fmaxf(t[r][3], 0.f);
    *(float4*)&ts[r][fg] = v;
  }
  __syncthreads();

  const int d4 = lane * 4;
  float u[8][4];
#pragma unroll
  for (int r = 0; r < 8; ++r) { u[r][0] = 0.f; u[r][1] = 0.f; u[r][2] = 0.f; u[r][3] = 0.f; }
  for (int kk = 0; kk < 256; kk += 4) {
    const int kg = wv * 256 + kk;
    float4 w2v[4];
#pragma unroll
    for (int k = 0; k < 4; ++k) w2v[k] = *(const float4*)&W2[(kg + k) * Dc + d4];
#pragma unroll
    for (int r = 0; r < 8; ++r) {
      const float4 h = *(const float4*)&ts[r][kg];
      const float hv[4] = {h.x, h.y, h.z, h.w};
#pragma unroll
      for (int k = 0; k < 4; ++k) {
        u[r][0] = fmaf(hv[k], w2v[k].x, u[r][0]);
        u[r][1] = fmaf(hv[k], w2v[k].y, u[r][1]);
        u[r][2] = fmaf(hv[k], w2v[k].z, u[r][2]);
        u[r][3] = fmaf(hv[k], w2v[k].w, u[r][3]);
      }
    }
  }
  __syncthreads();

  float* redb = &ts[0][0];
#pragma unroll
  for (int r = 0; r < 8; ++r) {
    float4 v; v.x = u[r][0]; v.y = u[r][1]; v.z = u[r][2]; v.w = u[r][3];
    *(float4*)&redb[(wv * 8 + r) * 256 + d4] = v;
  }
  __syncthreads();

  {
    const int r = tid >> 6;
    const int dg = (tid & 63) * 4;
    float4 s = *(const float4*)&redb[(0 * 8 + r) * 256 + dg];
#pragma unroll
    for (int w = 1; w < 8; ++w) {
      const float4 p = *(const float4*)&redb[(w * 8 + r) * 256 + dg];
      s.x += p.x; s.y += p.y; s.z += p.z; s.w += p.w;
    }
    const float4 x0 = *(const float4*)&x0s[r][dg];
    const float4 bb = *(const float4*)&b2f[dg];
    float4 e;
    e.x = (x0.x + s.x) + bb.x; e.y = (x0.y + s.y) + bb.y;
    e.z = (x0.z + s.z) + bb.z; e.w = (x0.w + s.w) + bb.w;
    *(float4*)&ws[OFF_ENC + (wg * 8 + r) * Dc + dg] = e;
    *(float4*)&encs[r][dg] = e;
  }
  __syncthreads();

  {
    const int f = tid & 255;
    const int rh = tid >> 8;
    float g[4];
    const float be1f = be1[f];
#pragma unroll
    for (int rr = 0; rr < 4; ++rr) g[rr] = be1f;
    for (int c = 0; c < Dc; ++c) {
      const float w = We1[c * Dc + f];
#pragma unroll
      for (int rr = 0; rr < 4; ++rr) g[rr] = fmaf(encs[rh * 4 + rr][c], w, g[rr]);
    }
    const float w2 = We2[f];
#pragma unroll
    for (int rr = 0; rr < 4; ++rr) {
      float p = fmaxf(g[rr], 0.f) * w2;
#pragma unroll
      for (int off = 32; off; off >>= 1) p += __shfl_down(p, off, 64);
      if (lane == 0) zred[wv][rr] = p;
    }
  }
  __syncthreads();
  if (tid < 8) {
    const int r = tid;
    const int wb = (r < 4) ? 0 : 4;
    const int rl = r & 3;
    const float z = ((zred[wb + 0][rl] + zred[wb + 1][rl]) + zred[wb + 2][rl]) +
                    zred[wb + 3][rl];
    ws[OFF_Z + wg * 8 + r] = z + be2[0];
  }
}

extern "C" void kernel_launch(void* const* d_in, const int* in_sizes, int n_in,
                              void* d_out, int out_size, void* d_ws, size_t ws_size,
                              hipStream_t stream) {
  const float* frames = (const float*)d_in[0];
  const float* cls    = (const float*)d_in[1];
  const float* Wq     = (const float*)d_in[2];
  const float* bq     = (const float*)d_in[3];
  const float* Wk     = (const float*)d_in[4];
  const float* bk     = (const float*)d_in[5];
  const float* Wv     = (const float*)d_in[6];
  const float* bv     = (const float*)d_in[7];
  const float* Wo     = (const float*)d_in[8];
  const float* bo     = (const float*)d_in[9];
  const float* g1     = (const float*)d_in[10];
  const float* b1     = (const float*)d_in[11];
  const float* g2     = (const float*)d_in[12];
  const float* b2     = (const float*)d_in[13];
  const float* W1     = (const float*)d_in[14];
  const float* b1f    = (const float*)d_in[15];
  const float* W2     = (const float*)d_in[16];
  const float* b2f    = (const float*)d_in[17];
  const float* We1    = (const float*)d_in[18];
  const float* be1    = (const float*)d_in[19];
  const float* We2    = (const float*)d_in[20];
  const float* be2    = (const float*)d_in[21];
  float* ws = (float*)d_ws;
  float* out = (float*)d_out;

  const size_t need = (size_t)(OFF_U + GSPLIT * NROWS * Dc) * sizeof(float);

  if (ws_size >= need) {
    void* args[24] = {
        (void*)&frames, (void*)&cls, (void*)&Wq, (void*)&bq, (void*)&Wk, (void*)&bk,
        (void*)&Wv, (void*)&bv, (void*)&Wo, (void*)&bo, (void*)&g1, (void*)&b1,
        (void*)&g2, (void*)&b2, (void*)&W1, (void*)&b1f, (void*)&W2, (void*)&b2f,
        (void*)&We1, (void*)&be1, (void*)&We2, (void*)&be2, (void*)&ws, (void*)&out};
    hipError_t e = hipLaunchCooperativeKernel((const void*)k_all, dim3(1024), dim3(256),
                                              args, 0, stream);
    if (e != hipSuccess) {
      (void)hipGetLastError();
      e = hipLaunchCooperativeKernel((const void*)k_all, dim3(512), dim3(256),
                                     args, 0, stream);
    }
    if (e == hipSuccess) return;
    (void)hipGetLastError();
    // multi-kernel fallback
    k_prep<<<Bc * Tc + 1, 256, 0, stream>>>(frames, cls, Wq, bq, Wk, bk, Wv, bv, Wo, g1, b1, ws);
    k_attn<<<Bc * Tc, 256, 0, stream>>>(cls, bo, g2, b2, ws);
    k_ffn16<<<NTASK_FFN, 256, 0, stream>>>(W1, b1f, W2, ws);
    k_z<<<Bc * Tc, 256, 0, stream>>>(b2f, We1, be1, We2, be2, ws);
    k_emit<<<Bc, 256, 0, stream>>>(ws, out);
  } else {
    k_prep<<<Bc * Tc + 1, 256, 0, stream>>>(frames, cls, Wq, bq, Wk, bk, Wv, bv, Wo, g1, b1, ws);
    k_fused<<<Bc * Tc, 512, 0, stream>>>(cls, bo, g2, b2, W1, b1f, W2, b2f, We1, be1, We2, be2, ws);
    k_emit<<<Bc, 256, 0, stream>>>(ws, out);
  }
}

// Round 3
// 324.032 us; speedup vs baseline: 2.8179x; 2.8179x over previous
//
#include <hip/hip_runtime.h>

#define DEV __device__ __forceinline__

constexpr int Bc = 2, Tc = 128, Dc = 256, Lc = 8, Hc = 4, DH = 64, Fc = 2048;
constexpr float EPS = 1e-5f, SCALE = 0.125f;  // 1/sqrt(64)
constexpr int NROWS = Bc * Tc * Lc;           // 2048 candidate rows
constexpr int SLAB = NROWS * Dc;              // 524288 floats

// ---- workspace layout (float offsets) ----
constexpr int OFF_K     = 0;                        // B*T*D frame keys
constexpr int OFF_VWOH  = OFF_K + Bc * Tc * Dc;     // B*T*H*D per-head v@Wo partials
constexpr int OFF_QCLS  = OFF_VWOH + Bc * Tc * Hc * Dc;
constexpr int OFF_KCLS  = OFF_QCLS + Dc;
constexpr int OFF_VWOHC = OFF_KCLS + Dc;            // H*D
constexpr int OFF_ENC   = OFF_VWOHC + Hc * Dc;      // B*T*L*D encoder CLS outputs
constexpr int OFF_Z     = OFF_ENC + SLAB;           // B*T*L eoc logits
// total ~0.86M floats ~= 3.4 MB

DEV int imin(int a, int b) { return a < b ? a : b; }

// block = 256 threads (4 waves). red must be shared float[4].
DEV float blockReduceSum(float v, float* red) {
#pragma unroll
  for (int off = 32; off; off >>= 1) v += __shfl_down(v, off, 64);
  const int lane = threadIdx.x & 63;
  const int w = threadIdx.x >> 6;
  __syncthreads();  // protect red from previous use
  if (lane == 0) red[w] = v;
  __syncthreads();
  return red[0] + red[1] + red[2] + red[3];
}

// ---- K1: one row per block. LN1 + k/v projections + per-head v@Wo; q for CLS row. ----
__global__ __launch_bounds__(256) void k_prep(
    const float* __restrict__ frames, const float* __restrict__ cls,
    const float* __restrict__ Wq, const float* __restrict__ bq,
    const float* __restrict__ Wk, const float* __restrict__ bk,
    const float* __restrict__ Wv, const float* __restrict__ bv,
    const float* __restrict__ Wo,
    const float* __restrict__ g1, const float* __restrict__ b1,
    float* __restrict__ ws) {
  __shared__ float hsm[Dc];
  __shared__ float vsm[Dc];
  __shared__ float red[4];
  const int d = threadIdx.x;
  const int r = blockIdx.x;  // 0..B*T-1 frames, B*T = cls

  const float x = (r < Bc * Tc) ? frames[r * Dc + d] : cls[d];
  const float s = blockReduceSum(x, red);
  const float m = s * (1.0f / Dc);
  const float c = x - m;
  const float var = blockReduceSum(c * c, red) * (1.0f / Dc);
  hsm[d] = c * (1.0f / sqrtf(var + EPS)) * g1[d] + b1[d];
  __syncthreads();

  float ka = bk[d], va = bv[d];
  for (int c2 = 0; c2 < Dc; ++c2) {
    const float h = hsm[c2];
    ka = fmaf(h, Wk[c2 * Dc + d], ka);
    va = fmaf(h, Wv[c2 * Dc + d], va);
  }
  if (r < Bc * Tc) ws[OFF_K + r * Dc + d] = ka;
  else             ws[OFF_KCLS + d] = ka;
  vsm[d] = va;
  __syncthreads();

#pragma unroll
  for (int hh = 0; hh < Hc; ++hh) {
    float acc = 0.f;
    for (int c2 = 0; c2 < DH; ++c2)
      acc = fmaf(vsm[hh * DH + c2], Wo[(hh * DH + c2) * Dc + d], acc);
    if (r < Bc * Tc) ws[OFF_VWOH + r * (Hc * Dc) + hh * Dc + d] = acc;
    else             ws[OFF_VWOHC + hh * Dc + d] = acc;
  }
  if (r == Bc * Tc) {
    float qa = bq[d];
    for (int c2 = 0; c2 < Dc; ++c2) qa = fmaf(hsm[c2], Wq[c2 * Dc + d], qa);
    ws[OFF_QCLS + d] = qa;
  }
}

// ---- K2: fully fused per (b,i), 1024 threads (16 waves -> 4 waves/SIMD).
// Attn phases run on threads 0-255 (identical arithmetic to the verified 512-thr
// version). Waves 8-15 pre-warm W1/W2 into this XCD's L2 during attn.
// GEMM1: thread owns 2 f-cols (per-f-col c-ascending fma chain unchanged -> bit-exact).
// GEMM2: wave (r, k-half) computes the four 256-k chunk partials of its row
// separately; the 8-partial reduce keeps the exact old chunk order -> bit-exact.
__global__ __launch_bounds__(1024) void k_mid(
    const float* __restrict__ cls, const float* __restrict__ bo,
    const float* __restrict__ g2, const float* __restrict__ b2,
    const float* __restrict__ W1, const float* __restrict__ b1f,
    const float* __restrict__ W2, const float* __restrict__ b2f,
    const float* __restrict__ We1, const float* __restrict__ be1,
    const float* __restrict__ We2, const float* __restrict__ be2,
    float* __restrict__ ws) {
  const int wg = blockIdx.x;  // b*T + i
  const int i = wg & (Tc - 1);
  const int tid = threadIdx.x;
  const int lane = tid & 63;
  const int lmax = imin(Tc - i, Lc);

  __shared__ __align__(16) float ts[8][2048];   // 64KB; aliased as redb[8][8][256]
  __shared__ __align__(16) float h2s[8][256];   // 8KB
  __shared__ __align__(16) float x0s[8][256];   // 8KB
  __shared__ __align__(16) float encs[8][256];  // 8KB
  __shared__ float sv[Hc][Lc + 1];
  __shared__ float aP[Lc][Hc][Lc + 1];
  __shared__ __align__(16) float redA[Lc][4];
  __shared__ __align__(16) float redB[Lc][4];
  __shared__ float zred[4][4][2];               // [row-grp][wave-in-grp][row-in-grp]

  // ---- L2 pre-warm (waves 8-15, before the first barrier) ----
  if (tid >= 512) {
    // 32 disjoint 128KB chunks of W1+W2; blocks stride-8 (same XCD) pick distinct chunks.
    const int chunk = (blockIdx.x >> 3) & 31;
    const float4* src = (chunk < 16) ? (const float4*)W1 : (const float4*)W2;
    const int base = (chunk & 15) * 8192;  // 16 chunks x 8192 float4 = 2MB each matrix
    const int t2 = tid - 512;
    float acc = 0.f;
    for (int it = t2; it < 8192; it += 512) {
      const float4 a = src[base + it];
      acc += a.x + a.y + a.z + a.w;
    }
    asm volatile("" ::"v"(acc));  // keep loads live; no store
  }

  // ---- scores: waves 0-3, wave = head ----
  if (tid < 256) {
    const int hh = tid >> 6;
    const float qv = ws[OFF_QCLS + hh * DH + lane];
    for (int j = 0; j <= Lc; ++j) {
      float p = 0.f;
      if (j == 0) p = qv * ws[OFF_KCLS + hh * DH + lane];
      else if (j - 1 < lmax) p = qv * ws[OFF_K + (wg + j - 1) * Dc + hh * DH + lane];
#pragma unroll
      for (int off = 32; off; off >>= 1) p += __shfl_down(p, off, 64);
      if (lane == 0) sv[hh][j] = p * SCALE;
    }
  }
  __syncthreads();

  // ---- softmax per candidate length ----
  if (tid < Lc * Hc) {
    const int l = (tid >> 2) + 1, h4 = tid & 3;
    if (l <= lmax) {
      float mx = -1e30f;
      for (int j = 0; j <= l; ++j) mx = fmaxf(mx, sv[h4][j]);
      float den = 0.f;
      for (int j = 0; j <= l; ++j) den += expf(sv[h4][j] - mx);
      const float inv = 1.f / den;
      for (int j = 0; j <= l; ++j) aP[l - 1][h4][j] = expf(sv[h4][j] - mx) * inv;
    }
  }
  __syncthreads();

  // ---- x0 accumulation + LN round 1 (threads 0-255, d = tid) ----
  float x0v[Lc];
  if (tid < 256) {
    const int d = tid;
    const float base = cls[d] + bo[d];
#pragma unroll
    for (int l = 0; l < Lc; ++l) x0v[l] = base;
    for (int j = 0; j <= lmax; ++j) {
      const float* vwp = (j == 0) ? (ws + OFF_VWOHC)
                                  : (ws + OFF_VWOH + (wg + j - 1) * (Hc * Dc));
      for (int h4 = 0; h4 < Hc; ++h4) {
        const float w = vwp[h4 * Dc + d];
        const int lstart = (j == 0) ? 1 : j;
        for (int l = lstart; l <= lmax; ++l) x0v[l - 1] = fmaf(aP[l - 1][h4][j], w, x0v[l - 1]);
      }
    }
#pragma unroll
    for (int l = 0; l < Lc; ++l) {
      float p = x0v[l];
#pragma unroll
      for (int off = 32; off; off >>= 1) p += __shfl_down(p, off, 64);
      if (lane == 0) redA[l][tid >> 6] = p;
    }
  }
  __syncthreads();

  float mean[Lc];
  if (tid < 256) {
#pragma unroll
    for (int l = 0; l < Lc; ++l) {
      const float4 s4 = *(const float4*)redA[l];
      mean[l] = (s4.x + s4.y + s4.z + s4.w) * (1.f / Dc);
    }
#pragma unroll
    for (int l = 0; l < Lc; ++l) {
      const float cv = x0v[l] - mean[l];
      float p = cv * cv;
#pragma unroll
      for (int off = 32; off; off >>= 1) p += __shfl_down(p, off, 64);
      if (lane == 0) redB[l][tid >> 6] = p;
    }
  }
  __syncthreads();

  if (tid < 256) {
    const int d = tid;
    const float g2d = g2[d], b2d = b2[d];
    for (int l = 1; l <= lmax; ++l) {
      const float4 s4 = *(const float4*)redB[l - 1];
      const float var = (s4.x + s4.y + s4.z + s4.w) * (1.f / Dc);
      const float rstd = 1.f / sqrtf(var + EPS);
      h2s[l - 1][d] = (x0v[l - 1] - mean[l - 1]) * rstd * g2d + b2d;
      x0s[l - 1][d] = x0v[l - 1];
    }
    for (int l = lmax + 1; l <= Lc; ++l) {
      h2s[l - 1][d] = 0.f;
      x0s[l - 1][d] = 0.f;
    }
  }
  __syncthreads();

  // ---- FFN phase 1: T = relu(h2 @ W1 + b1f); 1024 threads x 2 f-cols, no barriers ----
  {
    const int fg = tid * 2;  // thread owns 2 f-cols of 2048
    float t[8][2];
    {
      const float2 bb = *(const float2*)&b1f[fg];
#pragma unroll
      for (int r = 0; r < 8; ++r) { t[r][0] = bb.x; t[r][1] = bb.y; }
    }
    for (int c = 0; c < Dc; c += 4) {
      float2 w1v[4];
#pragma unroll
      for (int k = 0; k < 4; ++k) w1v[k] = *(const float2*)&W1[(c + k) * Fc + fg];
#pragma unroll
      for (int r = 0; r < 8; ++r) {
        const float4 h = *(const float4*)&h2s[r][c];
        const float hv[4] = {h.x, h.y, h.z, h.w};
#pragma unroll
        for (int k = 0; k < 4; ++k) {
          t[r][0] = fmaf(hv[k], w1v[k].x, t[r][0]);
          t[r][1] = fmaf(hv[k], w1v[k].y, t[r][1]);
        }
      }
    }
#pragma unroll
    for (int r = 0; r < 8; ++r) {
      float2 v;
      v.x = fmaxf(t[r][0], 0.f);
      v.y = fmaxf(t[r][1], 0.f);
      *(float2*)&ts[r][fg] = v;
    }
  }
  __syncthreads();

  // ---- FFN phase 2: wave (r, k-half) computes 4 chunk-partials of row r ----
  const int wv16 = tid >> 6;        // 0..15
  const int rw = wv16 >> 1;         // row 0..7
  const int kh = wv16 & 1;          // k-half 0..1
  const int d4 = lane * 4;
  float u[4][4];                    // [chunk][d-comp]
#pragma unroll
  for (int ch = 0; ch < 4; ++ch) { u[ch][0] = 0.f; u[ch][1] = 0.f; u[ch][2] = 0.f; u[ch][3] = 0.f; }
#pragma unroll
  for (int ch = 0; ch < 4; ++ch) {
    const int kbase = kh * 1024 + ch * 256;
    for (int kk = 0; kk < 256; kk += 4) {
      const int kg = kbase + kk;
      float4 w2v[4];
#pragma unroll
      for (int k = 0; k < 4; ++k) w2v[k] = *(const float4*)&W2[(kg + k) * Dc + d4];
      const float4 h = *(const float4*)&ts[rw][kg];
      const float hv[4] = {h.x, h.y, h.z, h.w};
#pragma unroll
      for (int k = 0; k < 4; ++k) {
        u[ch][0] = fmaf(hv[k], w2v[k].x, u[ch][0]);
        u[ch][1] = fmaf(hv[k], w2v[k].y, u[ch][1]);
        u[ch][2] = fmaf(hv[k], w2v[k].z, u[ch][2]);
        u[ch][3] = fmaf(hv[k], w2v[k].w, u[ch][3]);
      }
    }
  }
  __syncthreads();  // all ts reads done before aliasing as redb

  // ---- deterministic 8-partial reduce (redb[8 chunks][8 rows][256] aliases ts) ----
  float* redb = &ts[0][0];
#pragma unroll
  for (int ch = 0; ch < 4; ++ch) {
    const int chunkid = kh * 4 + ch;  // matches old wave-slice index
    float4 v; v.x = u[ch][0]; v.y = u[ch][1]; v.z = u[ch][2]; v.w = u[ch][3];
    *(float4*)&redb[(chunkid * 8 + rw) * 256 + d4] = v;
  }
  __syncthreads();

  // ---- enc = x0 + U + b2f; threads 0-511, identical order to verified kernel ----
  if (tid < 512) {
    const int r = tid >> 6;         // row
    const int dg = (tid & 63) * 4;  // d-group
    float4 s = *(const float4*)&redb[(0 * 8 + r) * 256 + dg];
#pragma unroll
    for (int w = 1; w < 8; ++w) {
      const float4 p = *(const float4*)&redb[(w * 8 + r) * 256 + dg];
      s.x += p.x; s.y += p.y; s.z += p.z; s.w += p.w;
    }
    const float4 x0 = *(const float4*)&x0s[r][dg];
    const float4 bb = *(const float4*)&b2f[dg];
    float4 e;
    e.x = (x0.x + s.x) + bb.x; e.y = (x0.y + s.y) + bb.y;
    e.z = (x0.z + s.z) + bb.z; e.w = (x0.w + s.w) + bb.w;
    *(float4*)&ws[OFF_ENC + (wg * 8 + r) * Dc + dg] = e;
    *(float4*)&encs[r][dg] = e;
  }
  __syncthreads();

  // ---- z = relu(enc@We1+be1)@We2 + be2; 4 row-groups x 2 rows, bit-exact chains ----
  {
    const int f = tid & 255;        // column of We1
    const int rh = tid >> 8;        // row-group 0..3 (rows rh*2, rh*2+1)
    const int wvl = (tid >> 6) & 3; // wave within group (f = wvl*64 + lane)
    float gr[2];
    const float be1f = be1[f];
#pragma unroll
    for (int rr = 0; rr < 2; ++rr) gr[rr] = be1f;
    for (int c = 0; c < Dc; ++c) {
      const float w = We1[c * Dc + f];
#pragma unroll
      for (int rr = 0; rr < 2; ++rr) gr[rr] = fmaf(encs[rh * 2 + rr][c], w, gr[rr]);
    }
    const float w2 = We2[f];
#pragma unroll
    for (int rr = 0; rr < 2; ++rr) {
      float p = fmaxf(gr[rr], 0.f) * w2;
#pragma unroll
      for (int off = 32; off; off >>= 1) p += __shfl_down(p, off, 64);
      if (lane == 0) zred[rh][wvl][rr] = p;
    }
  }
  __syncthreads();
  if (tid < 8) {
    const int r = tid;
    const int rh = r >> 1, rr = r & 1;
    const float z = ((zred[rh][0][rr] + zred[rh][1][rr]) + zred[rh][2][rr]) +
                    zred[rh][3][rr];
    ws[OFF_Z + wg * 8 + r] = z + be2[0];
  }
}

// ---- K3: select lstar (fused) + sequential walk via wave shuffles + emit ----
__global__ __launch_bounds__(256) void k_emit(float* __restrict__ ws, float* __restrict__ out) {
  const int b = blockIdx.x;
  const int tid = threadIdx.x;
  __shared__ int lst[Tc];
  __shared__ int path[Tc];
  __shared__ int cnt_s;
  if (tid < Tc) {
    const int i = tid;
    const int lmax = imin(Tc - i, Lc);
    const float* z = ws + OFF_Z + (b * Tc + i) * Lc;
    int ls = lmax;
    for (int l = 1; l <= lmax; ++l) {
      if (z[l - 1] > 0.f) { ls = l; break; }
    }
    lst[tid] = ls;
  }
  __syncthreads();
  if (tid < 64) {  // wave 0: walk via register shuffles (low-latency chain)
    const int a0 = lst[tid], a1 = lst[64 + tid];
    int cur = 0, s = 0;
    while (cur < Tc) {
      const int l = (cur < 64) ? __shfl(a0, cur, 64) : __shfl(a1, cur - 64, 64);
      if (tid == 0) path[s] = cur * Lc + l - 1;
      ++s;
      cur += l;
    }
    if (tid == 0) cnt_s = s;
  }
  __syncthreads();
  const int c = cnt_s;
  for (int s0 = 0; s0 < Tc; s0 += 8) {
    float v[8];
#pragma unroll
    for (int k = 0; k < 8; ++k) {
      const int s = s0 + k;
      v[k] = (s < c) ? ws[OFF_ENC + (b * Tc * Lc + path[s]) * Dc + tid] : 0.f;
    }
#pragma unroll
    for (int k = 0; k < 8; ++k) out[(b * Tc + s0 + k) * Dc + tid] = v[k];
  }
  if (tid == 0) out[Bc * Tc * Dc + b] = (float)c;
}

extern "C" void kernel_launch(void* const* d_in, const int* in_sizes, int n_in,
                              void* d_out, int out_size, void* d_ws, size_t ws_size,
                              hipStream_t stream) {
  const float* frames = (const float*)d_in[0];
  const float* cls    = (const float*)d_in[1];
  const float* Wq     = (const float*)d_in[2];
  const float* bq     = (const float*)d_in[3];
  const float* Wk     = (const float*)d_in[4];
  const float* bk     = (const float*)d_in[5];
  const float* Wv     = (const float*)d_in[6];
  const float* bv     = (const float*)d_in[7];
  const float* Wo     = (const float*)d_in[8];
  const float* bo     = (const float*)d_in[9];
  const float* g1     = (const float*)d_in[10];
  const float* b1     = (const float*)d_in[11];
  const float* g2     = (const float*)d_in[12];
  const float* b2     = (const float*)d_in[13];
  const float* W1     = (const float*)d_in[14];
  const float* b1f    = (const float*)d_in[15];
  const float* W2     = (const float*)d_in[16];
  const float* b2f    = (const float*)d_in[17];
  const float* We1    = (const float*)d_in[18];
  const float* be1    = (const float*)d_in[19];
  const float* We2    = (const float*)d_in[20];
  const float* be2    = (const float*)d_in[21];
  float* ws = (float*)d_ws;
  float* out = (float*)d_out;

  k_prep<<<Bc * Tc + 1, 256, 0, stream>>>(frames, cls, Wq, bq, Wk, bk, Wv, bv, Wo, g1, b1, ws);
  k_mid<<<Bc * Tc, 1024, 0, stream>>>(cls, bo, g2, b2, W1, b1f, W2, b2f, We1, be1, We2, be2, ws);
  k_emit<<<Bc, 256, 0, stream>>>(ws, out);
}

// Round 4
// 288.570 us; speedup vs baseline: 3.1642x; 1.1229x over previous
//
#include <hip/hip_runtime.h>

#define DEV __device__ __forceinline__

constexpr int Bc = 2, Tc = 128, Dc = 256, Lc = 8, Hc = 4, DH = 64, Fc = 2048;
constexpr float EPS = 1e-5f, SCALE = 0.125f;  // 1/sqrt(64)
constexpr int NROWS = Bc * Tc * Lc;           // 2048 candidate rows
constexpr int SLAB = NROWS * Dc;              // 524288 floats

// ---- workspace layout (float offsets) ----
constexpr int OFF_K     = 0;                        // B*T*D frame keys
constexpr int OFF_VWOH  = OFF_K + Bc * Tc * Dc;     // B*T*H*D per-head v@Wo partials
constexpr int OFF_QCLS  = OFF_VWOH + Bc * Tc * Hc * Dc;
constexpr int OFF_KCLS  = OFF_QCLS + Dc;
constexpr int OFF_VWOHC = OFF_KCLS + Dc;            // H*D
constexpr int OFF_ENC   = OFF_VWOHC + Hc * Dc;      // B*T*L*D x0, then enc (in-place)
constexpr int OFF_Z     = OFF_ENC + SLAB;           // B*T*L eoc logits
constexpr int OFF_H2    = OFF_Z + NROWS;            // (unused in main path; layout kept)
constexpr int OFF_U     = OFF_H2 + SLAB;            // G partial-U slabs [G][NROWS][D]

constexpr int RB = 16;                 // rows per FFN block (32KB LDS -> 4 blocks/CU)
constexpr int GSPLIT = 8;              // F-dimension split (preserves U0..U7 sum order)
constexpr int FS = Fc / GSPLIT;        // 256 f-cols per slice
constexpr int NT_FZ = (NROWS / RB) * GSPLIT;  // 1024 blocks

DEV int imin(int a, int b) { return a < b ? a : b; }

// block = 256 threads (4 waves). red must be shared float[4].
DEV float blockReduceSum(float v, float* red) {
#pragma unroll
  for (int off = 32; off; off >>= 1) v += __shfl_down(v, off, 64);
  const int lane = threadIdx.x & 63;
  const int w = threadIdx.x >> 6;
  __syncthreads();  // protect red from previous use
  if (lane == 0) red[w] = v;
  __syncthreads();
  return red[0] + red[1] + red[2] + red[3];
}

// ---- K1: one row per block. LN1 + k/v projections + per-head v@Wo; q for CLS row. ----
__global__ __launch_bounds__(256) void k_prep(
    const float* __restrict__ frames, const float* __restrict__ cls,
    const float* __restrict__ Wq, const float* __restrict__ bq,
    const float* __restrict__ Wk, const float* __restrict__ bk,
    const float* __restrict__ Wv, const float* __restrict__ bv,
    const float* __restrict__ Wo,
    const float* __restrict__ g1, const float* __restrict__ b1,
    float* __restrict__ ws) {
  __shared__ float hsm[Dc];
  __shared__ float vsm[Dc];
  __shared__ float red[4];
  const int d = threadIdx.x;
  const int r = blockIdx.x;  // 0..B*T-1 frames, B*T = cls

  const float x = (r < Bc * Tc) ? frames[r * Dc + d] : cls[d];
  const float s = blockReduceSum(x, red);
  const float m = s * (1.0f / Dc);
  const float c = x - m;
  const float var = blockReduceSum(c * c, red) * (1.0f / Dc);
  hsm[d] = c * (1.0f / sqrtf(var + EPS)) * g1[d] + b1[d];
  __syncthreads();

  float ka = bk[d], va = bv[d];
  for (int c2 = 0; c2 < Dc; ++c2) {
    const float h = hsm[c2];
    ka = fmaf(h, Wk[c2 * Dc + d], ka);
    va = fmaf(h, Wv[c2 * Dc + d], va);
  }
  if (r < Bc * Tc) ws[OFF_K + r * Dc + d] = ka;
  else             ws[OFF_KCLS + d] = ka;
  vsm[d] = va;
  __syncthreads();

#pragma unroll
  for (int hh = 0; hh < Hc; ++hh) {
    float acc = 0.f;
    for (int c2 = 0; c2 < DH; ++c2)
      acc = fmaf(vsm[hh * DH + c2], Wo[(hh * DH + c2) * Dc + d], acc);
    if (r < Bc * Tc) ws[OFF_VWOH + r * (Hc * Dc) + hh * Dc + d] = acc;
    else             ws[OFF_VWOHC + hh * Dc + d] = acc;
  }
  if (r == Bc * Tc) {
    float qa = bq[d];
    for (int c2 = 0; c2 < Dc; ++c2) qa = fmaf(hsm[c2], Wq[c2 * Dc + d], qa);
    ws[OFF_QCLS + d] = qa;
  }
}

// ---- K2: attn prologue (2 (b,i) groups, h2 -> LDS; x0 -> ws by g==0 blocks only)
//      + batched FFN: RB=16 rows x one 256-wide F-slice g. 1024 blocks, 32KB LDS
//      -> 4 blocks/CU -> 4 waves/SIMD. All per-element fma chains identical to the
//      verified round-1 kernels (GEMM chains are RB-independent).
__global__ __launch_bounds__(256) void k_fz(
    const float* __restrict__ cls, const float* __restrict__ bo,
    const float* __restrict__ g2, const float* __restrict__ b2,
    const float* __restrict__ W1, const float* __restrict__ b1f,
    const float* __restrict__ W2, float* __restrict__ ws) {
  const int rb = blockIdx.x >> 3;   // row-block 0..127 (16 rows = 2 (b,i) groups)
  const int g = blockIdx.x & 7;     // F-slice
  const int r0 = rb * RB;
  const int tid = threadIdx.x;
  const int lane = tid & 63;

  __shared__ __align__(16) float h2s[RB][Dc];  // 16KB
  __shared__ __align__(16) float Ts[RB][FS];   // 16KB
  __shared__ float sv[Hc][Lc + 1];
  __shared__ float aP[Lc][Hc][Lc + 1];
  __shared__ __align__(16) float redA[Lc][4];
  __shared__ __align__(16) float redB[Lc][4];

  // ======== attn prologue: groups wg = rb*2, rb*2+1 ========
  for (int grp = 0; grp < 2; ++grp) {
    const int wg = rb * 2 + grp;
    const int i = wg & (Tc - 1);
    const int lmax = imin(Tc - i, Lc);

    // ---- scores: wave = head ----
    {
      const int hh = tid >> 6;
      const float qv = ws[OFF_QCLS + hh * DH + lane];
      for (int j = 0; j <= Lc; ++j) {
        float p = 0.f;
        if (j == 0) p = qv * ws[OFF_KCLS + hh * DH + lane];
        else if (j - 1 < lmax) p = qv * ws[OFF_K + (wg + j - 1) * Dc + hh * DH + lane];
#pragma unroll
        for (int off = 32; off; off >>= 1) p += __shfl_down(p, off, 64);
        if (lane == 0) sv[hh][j] = p * SCALE;
      }
    }
    __syncthreads();

    // ---- softmax per candidate length ----
    if (tid < Lc * Hc) {
      const int l = (tid >> 2) + 1, h4 = tid & 3;
      if (l <= lmax) {
        float mx = -1e30f;
        for (int j = 0; j <= l; ++j) mx = fmaxf(mx, sv[h4][j]);
        float den = 0.f;
        for (int j = 0; j <= l; ++j) den += expf(sv[h4][j] - mx);
        const float inv = 1.f / den;
        for (int j = 0; j <= l; ++j) aP[l - 1][h4][j] = expf(sv[h4][j] - mx) * inv;
      }
    }
    __syncthreads();

    // ---- x0 accumulation + LN round 1 (d = tid) ----
    const int d = tid;
    float x0v[Lc];
    {
      const float base = cls[d] + bo[d];
#pragma unroll
      for (int l = 0; l < Lc; ++l) x0v[l] = base;
      for (int j = 0; j <= lmax; ++j) {
        const float* vwp = (j == 0) ? (ws + OFF_VWOHC)
                                    : (ws + OFF_VWOH + (wg + j - 1) * (Hc * Dc));
        for (int h4 = 0; h4 < Hc; ++h4) {
          const float w = vwp[h4 * Dc + d];
          const int lstart = (j == 0) ? 1 : j;
          for (int l = lstart; l <= lmax; ++l) x0v[l - 1] = fmaf(aP[l - 1][h4][j], w, x0v[l - 1]);
        }
      }
#pragma unroll
      for (int l = 0; l < Lc; ++l) {
        float p = x0v[l];
#pragma unroll
        for (int off = 32; off; off >>= 1) p += __shfl_down(p, off, 64);
        if (lane == 0) redA[l][tid >> 6] = p;
      }
    }
    __syncthreads();

    float mean[Lc];
    {
#pragma unroll
      for (int l = 0; l < Lc; ++l) {
        const float4 s4 = *(const float4*)redA[l];
        mean[l] = (s4.x + s4.y + s4.z + s4.w) * (1.f / Dc);
      }
#pragma unroll
      for (int l = 0; l < Lc; ++l) {
        const float cv = x0v[l] - mean[l];
        float p = cv * cv;
#pragma unroll
        for (int off = 32; off; off >>= 1) p += __shfl_down(p, off, 64);
        if (lane == 0) redB[l][tid >> 6] = p;
      }
    }
    __syncthreads();

    {
      const float g2d = g2[d], b2d = b2[d];
      for (int l = 1; l <= lmax; ++l) {
        const float4 s4 = *(const float4*)redB[l - 1];
        const float var = (s4.x + s4.y + s4.z + s4.w) * (1.f / Dc);
        const float rstd = 1.f / sqrtf(var + EPS);
        h2s[grp * Lc + l - 1][d] = (x0v[l - 1] - mean[l - 1]) * rstd * g2d + b2d;
        if (g == 0) ws[OFF_ENC + (wg * Lc + l - 1) * Dc + d] = x0v[l - 1];
      }
      for (int l = lmax + 1; l <= Lc; ++l) {
        h2s[grp * Lc + l - 1][d] = 0.f;
        if (g == 0) ws[OFF_ENC + (wg * Lc + l - 1) * Dc + d] = 0.f;
      }
    }
    __syncthreads();
  }

  // ======== FFN ========
  const int cg = tid & 63;
  const int rg = tid >> 6;

  // ---- GEMM1: T = relu(h2 @ W1_slice + b1f) ----
  const int f0 = g * FS + cg * 4;
  float t[4][4];
  {
    const float4 bb = *(const float4*)&b1f[f0];
#pragma unroll
    for (int r = 0; r < 4; ++r) { t[r][0] = bb.x; t[r][1] = bb.y; t[r][2] = bb.z; t[r][3] = bb.w; }
  }
  {
    const float* Wp = W1 + f0;
    float4 wn[4];
#pragma unroll
    for (int k = 0; k < 4; ++k) wn[k] = *(const float4*)&Wp[k * Fc];
    for (int c = 0; c < Dc; c += 4) {
      float4 wc[4];
#pragma unroll
      for (int k = 0; k < 4; ++k) wc[k] = wn[k];
      {  // branchless 1-deep prefetch (re-reads last rows on final iter)
        const float* Wn = Wp + imin(c + 4, Dc - 4) * Fc;
#pragma unroll
        for (int k = 0; k < 4; ++k) wn[k] = *(const float4*)&Wn[k * Fc];
      }
#pragma unroll
      for (int r = 0; r < 4; ++r) {
        const float4 h = *(const float4*)&h2s[rg * 4 + r][c];
        const float hv[4] = {h.x, h.y, h.z, h.w};
#pragma unroll
        for (int k = 0; k < 4; ++k) {
          t[r][0] = fmaf(hv[k], wc[k].x, t[r][0]);
          t[r][1] = fmaf(hv[k], wc[k].y, t[r][1]);
          t[r][2] = fmaf(hv[k], wc[k].z, t[r][2]);
          t[r][3] = fmaf(hv[k], wc[k].w, t[r][3]);
        }
      }
    }
  }
#pragma unroll
  for (int r = 0; r < 4; ++r) {
    float4 v;
    v.x = fmaxf(t[r][0], 0.f); v.y = fmaxf(t[r][1], 0.f);
    v.z = fmaxf(t[r][2], 0.f); v.w = fmaxf(t[r][3], 0.f);
    *(float4*)&Ts[rg * 4 + r][cg * 4] = v;
  }
  __syncthreads();

  // ---- GEMM2: U_partial = T @ W2_slice; wave's W2 slice amortized over its 4 rows ----
  float u[4][4];
#pragma unroll
  for (int r = 0; r < 4; ++r) { u[r][0] = 0.f; u[r][1] = 0.f; u[r][2] = 0.f; u[r][3] = 0.f; }
  {
    const float* Wp = W2 + g * FS * Dc + cg * 4;
    float4 wn[4];
#pragma unroll
    for (int k = 0; k < 4; ++k) wn[k] = *(const float4*)&Wp[k * Dc];
    for (int kk = 0; kk < FS; kk += 4) {
      float4 wc[4];
#pragma unroll
      for (int k = 0; k < 4; ++k) wc[k] = wn[k];
      {
        const float* Wn = Wp + imin(kk + 4, FS - 4) * Dc;
#pragma unroll
        for (int k = 0; k < 4; ++k) wn[k] = *(const float4*)&Wn[k * Dc];
      }
#pragma unroll
      for (int r = 0; r < 4; ++r) {
        const float4 a = *(const float4*)&Ts[rg * 4 + r][kk];
        const float av[4] = {a.x, a.y, a.z, a.w};
#pragma unroll
        for (int k = 0; k < 4; ++k) {
          u[r][0] = fmaf(av[k], wc[k].x, u[r][0]);
          u[r][1] = fmaf(av[k], wc[k].y, u[r][1]);
          u[r][2] = fmaf(av[k], wc[k].z, u[r][2]);
          u[r][3] = fmaf(av[k], wc[k].w, u[r][3]);
        }
      }
    }
  }
#pragma unroll
  for (int r = 0; r < 4; ++r) {
    float4 v; v.x = u[r][0]; v.y = u[r][1]; v.z = u[r][2]; v.w = u[r][3];
    *(float4*)&ws[OFF_U + (g * NROWS + r0 + rg * 4 + r) * Dc + cg * 4] = v;
  }
}

// ---- K3: per (b,i): enc = x0 + sum_g U_g + b2f (exact old order), then z. 512 thr. ----
__global__ __launch_bounds__(512) void k_z(
    const float* __restrict__ b2f,
    const float* __restrict__ We1, const float* __restrict__ be1,
    const float* __restrict__ We2, const float* __restrict__ be2,
    float* __restrict__ ws) {
  const int wg = blockIdx.x;
  const int tid = threadIdx.x;
  const int wv = tid >> 6, lane = tid & 63;

  __shared__ __align__(16) float encs[Lc][Dc];  // 8 KB
  __shared__ float zred[8][4];

  // ---- reduce partials ----
  {
    const int r = tid >> 6;          // 0..7 (row)
    const int dg = (tid & 63) * 4;   // d-group
    const int row = wg * Lc + r;
    float4 s = *(const float4*)&ws[OFF_U + (0 * NROWS + row) * Dc + dg];
#pragma unroll
    for (int g = 1; g < GSPLIT; ++g) {
      const float4 p = *(const float4*)&ws[OFF_U + (g * NROWS + row) * Dc + dg];
      s.x += p.x; s.y += p.y; s.z += p.z; s.w += p.w;
    }
    const float4 x0 = *(const float4*)&ws[OFF_ENC + row * Dc + dg];
    const float4 bb = *(const float4*)&b2f[dg];
    float4 e;
    e.x = (x0.x + s.x) + bb.x; e.y = (x0.y + s.y) + bb.y;
    e.z = (x0.z + s.z) + bb.z; e.w = (x0.w + s.w) + bb.w;
    *(float4*)&ws[OFF_ENC + row * Dc + dg] = e;
    *(float4*)&encs[r][dg] = e;
  }
  __syncthreads();

  // ---- z = relu(enc@We1+be1)@We2 + be2 ----
  {
    const int f = tid & 255;  // waves 0-3: rows 0-3; waves 4-7: rows 4-7
    const int rh = tid >> 8;
    float gr[4];
    const float be1f = be1[f];
#pragma unroll
    for (int rr = 0; rr < 4; ++rr) gr[rr] = be1f;
    for (int c = 0; c < Dc; c += 4) {
      const float w0 = We1[(c + 0) * Dc + f];
      const float w1 = We1[(c + 1) * Dc + f];
      const float w2 = We1[(c + 2) * Dc + f];
      const float w3 = We1[(c + 3) * Dc + f];
#pragma unroll
      for (int rr = 0; rr < 4; ++rr) {
        const float4 e = *(const float4*)&encs[rh * 4 + rr][c];
        gr[rr] = fmaf(e.x, w0, gr[rr]);
        gr[rr] = fmaf(e.y, w1, gr[rr]);
        gr[rr] = fmaf(e.z, w2, gr[rr]);
        gr[rr] = fmaf(e.w, w3, gr[rr]);
      }
    }
    const float w2v = We2[f];
#pragma unroll
    for (int rr = 0; rr < 4; ++rr) {
      float p = fmaxf(gr[rr], 0.f) * w2v;
#pragma unroll
      for (int off = 32; off; off >>= 1) p += __shfl_down(p, off, 64);
      if (lane == 0) zred[wv][rr] = p;
    }
  }
  __syncthreads();
  if (tid < 8) {
    const int r = tid;
    const int wb = (r < 4) ? 0 : 4;
    const int rl = r & 3;
    const float z = ((zred[wb + 0][rl] + zred[wb + 1][rl]) + zred[wb + 2][rl]) +
                    zred[wb + 3][rl];
    ws[OFF_Z + wg * 8 + r] = z + be2[0];
  }
}

// ---- K4: select lstar (fused) + sequential walk via wave shuffles + emit ----
__global__ __launch_bounds__(256) void k_emit(float* __restrict__ ws, float* __restrict__ out) {
  const int b = blockIdx.x;
  const int tid = threadIdx.x;
  __shared__ int lst[Tc];
  __shared__ int path[Tc];
  __shared__ int cnt_s;
  if (tid < Tc) {
    const int i = tid;
    const int lmax = imin(Tc - i, Lc);
    const float* z = ws + OFF_Z + (b * Tc + i) * Lc;
    int ls = lmax;
    for (int l = 1; l <= lmax; ++l) {
      if (z[l - 1] > 0.f) { ls = l; break; }
    }
    lst[tid] = ls;
  }
  __syncthreads();
  if (tid < 64) {  // wave 0: walk via register shuffles (low-latency chain)
    const int a0 = lst[tid], a1 = lst[64 + tid];
    int cur = 0, s = 0;
    while (cur < Tc) {
      const int l = (cur < 64) ? __shfl(a0, cur, 64) : __shfl(a1, cur - 64, 64);
      if (tid == 0) path[s] = cur * Lc + l - 1;
      ++s;
      cur += l;
    }
    if (tid == 0) cnt_s = s;
  }
  __syncthreads();
  const int c = cnt_s;
  for (int s0 = 0; s0 < Tc; s0 += 8) {
    float v[8];
#pragma unroll
    for (int k = 0; k < 8; ++k) {
      const int s = s0 + k;
      v[k] = (s < c) ? ws[OFF_ENC + (b * Tc * Lc + path[s]) * Dc + tid] : 0.f;
    }
#pragma unroll
    for (int k = 0; k < 8; ++k) out[(b * Tc + s0 + k) * Dc + tid] = v[k];
  }
  if (tid == 0) out[Bc * Tc * Dc + b] = (float)c;
}

// ---- tiny-workspace fallback: round-0 fully-fused K2 (verified) ----
__global__ __launch_bounds__(512) void k_fused(
    const float* __restrict__ cls, const float* __restrict__ bo,
    const float* __restrict__ g2, const float* __restrict__ b2,
    const float* __restrict__ W1, const float* __restrict__ b1f,
    const float* __restrict__ W2, const float* __restrict__ b2f,
    const float* __restrict__ We1, const float* __restrict__ be1,
    const float* __restrict__ We2, const float* __restrict__ be2,
    float* __restrict__ ws) {
  const int wg = blockIdx.x;
  const int i = wg & (Tc - 1);
  const int tid = threadIdx.x;
  const int wv = tid >> 6, lane = tid & 63;
  const int lmax = imin(Tc - i, Lc);

  __shared__ __align__(16) float ts[8][2048];
  __shared__ __align__(16) float h2s[8][256];
  __shared__ __align__(16) float x0s[8][256];
  __shared__ __align__(16) float encs[8][256];
  __shared__ float sv[Hc][Lc + 1];
  __shared__ float aP[Lc][Hc][Lc + 1];
  __shared__ __align__(16) float redA[Lc][4];
  __shared__ __align__(16) float redB[Lc][4];
  __shared__ float zred[8][4];

  if (tid < 256) {
    const int hh = tid >> 6;
    const float qv = ws[OFF_QCLS + hh * DH + lane];
    for (int j = 0; j <= Lc; ++j) {
      float p = 0.f;
      if (j == 0) p = qv * ws[OFF_KCLS + hh * DH + lane];
      else if (j - 1 < lmax) p = qv * ws[OFF_K + (wg + j - 1) * Dc + hh * DH + lane];
#pragma unroll
      for (int off = 32; off; off >>= 1) p += __shfl_down(p, off, 64);
      if (lane == 0) sv[hh][j] = p * SCALE;
    }
  }
  __syncthreads();

  if (tid < Lc * Hc) {
    const int l = (tid >> 2) + 1, h4 = tid & 3;
    if (l <= lmax) {
      float mx = -1e30f;
      for (int j = 0; j <= l; ++j) mx = fmaxf(mx, sv[h4][j]);
      float den = 0.f;
      for (int j = 0; j <= l; ++j) den += expf(sv[h4][j] - mx);
      const float inv = 1.f / den;
      for (int j = 0; j <= l; ++j) aP[l - 1][h4][j] = expf(sv[h4][j] - mx) * inv;
    }
  }
  __syncthreads();

  float x0v[Lc];
  if (tid < 256) {
    const int d = tid;
    const float base = cls[d] + bo[d];
#pragma unroll
    for (int l = 0; l < Lc; ++l) x0v[l] = base;
    for (int j = 0; j <= lmax; ++j) {
      const float* vwp = (j == 0) ? (ws + OFF_VWOHC)
                                  : (ws + OFF_VWOH + (wg + j - 1) * (Hc * Dc));
      for (int h4 = 0; h4 < Hc; ++h4) {
        const float w = vwp[h4 * Dc + d];
        const int lstart = (j == 0) ? 1 : j;
        for (int l = lstart; l <= lmax; ++l) x0v[l - 1] = fmaf(aP[l - 1][h4][j], w, x0v[l - 1]);
      }
    }
#pragma unroll
    for (int l = 0; l < Lc; ++l) {
      float p = x0v[l];
#pragma unroll
      for (int off = 32; off; off >>= 1) p += __shfl_down(p, off, 64);
      if (lane == 0) redA[l][tid >> 6] = p;
    }
  }
  __syncthreads();

  float mean[Lc];
  if (tid < 256) {
#pragma unroll
    for (int l = 0; l < Lc; ++l) {
      const float4 s4 = *(const float4*)redA[l];
      mean[l] = (s4.x + s4.y + s4.z + s4.w) * (1.f / Dc);
    }
#pragma unroll
    for (int l = 0; l < Lc; ++l) {
      const float cv = x0v[l] - mean[l];
      float p = cv * cv;
#pragma unroll
      for (int off = 32; off; off >>= 1) p += __shfl_down(p, off, 64);
      if (lane == 0) redB[l][tid >> 6] = p;
    }
  }
  __syncthreads();

  if (tid < 256) {
    const int d = tid;
    const float g2d = g2[d], b2d = b2[d];
    for (int l = 1; l <= lmax; ++l) {
      const float4 s4 = *(const float4*)redB[l - 1];
      const float var = (s4.x + s4.y + s4.z + s4.w) * (1.f / Dc);
      const float rstd = 1.f / sqrtf(var + EPS);
      h2s[l - 1][d] = (x0v[l - 1] - mean[l - 1]) * rstd * g2d + b2d;
      x0s[l - 1][d] = x0v[l - 1];
    }
    for (int l = lmax + 1; l <= Lc; ++l) {
      h2s[l - 1][d] = 0.f;
      x0s[l - 1][d] = 0.f;
    }
  }
  __syncthreads();

  const int fg = tid * 4;
  float t[8][4];
  {
    const float4 bb = *(const float4*)&b1f[fg];
#pragma unroll
    for (int r = 0; r < 8; ++r) { t[r][0] = bb.x; t[r][1] = bb.y; t[r][2] = bb.z; t[r][3] = bb.w; }
  }
  for (int c = 0; c < Dc; c += 4) {
    float4 w1v[4];
#pragma unroll
    for (int k = 0; k < 4; ++k) w1v[k] = *(const float4*)&W1[(c + k) * Fc + fg];
#pragma unroll
    for (int r = 0; r < 8; ++r) {
      const float4 h = *(const float4*)&h2s[r][c];
      const float hv[4] = {h.x, h.y, h.z, h.w};
#pragma unroll
      for (int k = 0; k < 4; ++k) {
        t[r][0] = fmaf(hv[k], w1v[k].x, t[r][0]);
        t[r][1] = fmaf(hv[k], w1v[k].y, t[r][1]);
        t[r][2] = fmaf(hv[k], w1v[k].z, t[r][2]);
        t[r][3] = fmaf(hv[k], w1v[k].w, t[r][3]);
      }
    }
  }
#pragma unroll
  for (int r = 0; r < 8; ++r) {
    float4 v;
    v.x = fmaxf(t[r][0], 0.f); v.y = fmaxf(t[r][1], 0.f);
    v.z = fmaxf(t[r][2], 0.f); v.w = fmaxf(t[r][3], 0.f);
    *(float4*)&ts[r][fg] = v;
  }
  __syncthreads();

  const int d4 = lane * 4;
  float u[8][4];
#pragma unroll
  for (int r = 0; r < 8; ++r) { u[r][0] = 0.f; u[r][1] = 0.f; u[r][2] = 0.f; u[r][3] = 0.f; }
  for (int kk = 0; kk < 256; kk += 4) {
    const int kg = wv * 256 + kk;
    float4 w2v[4];
#pragma unroll
    for (int k = 0; k < 4; ++k) w2v[k] = *(const float4*)&W2[(kg + k) * Dc + d4];
#pragma unroll
    for (int r = 0; r < 8; ++r) {
      const float4 h = *(const float4*)&ts[r][kg];
      const float hv[4] = {h.x, h.y, h.z, h.w};
#pragma unroll
      for (int k = 0; k < 4; ++k) {
        u[r][0] = fmaf(hv[k], w2v[k].x, u[r][0]);
        u[r][1] = fmaf(hv[k], w2v[k].y, u[r][1]);
        u[r][2] = fmaf(hv[k], w2v[k].z, u[r][2]);
        u[r][3] = fmaf(hv[k], w2v[k].w, u[r][3]);
      }
    }
  }
  __syncthreads();

  float* redb = &ts[0][0];
#pragma unroll
  for (int r = 0; r < 8; ++r) {
    float4 v; v.x = u[r][0]; v.y = u[r][1]; v.z = u[r][2]; v.w = u[r][3];
    *(float4*)&redb[(wv * 8 + r) * 256 + d4] = v;
  }
  __syncthreads();

  {
    const int r = tid >> 6;
    const int dg = (tid & 63) * 4;
    float4 s = *(const float4*)&redb[(0 * 8 + r) * 256 + dg];
#pragma unroll
    for (int w = 1; w < 8; ++w) {
      const float4 p = *(const float4*)&redb[(w * 8 + r) * 256 + dg];
      s.x += p.x; s.y += p.y; s.z += p.z; s.w += p.w;
    }
    const float4 x0 = *(const float4*)&x0s[r][dg];
    const float4 bb = *(const float4*)&b2f[dg];
    float4 e;
    e.x = (x0.x + s.x) + bb.x; e.y = (x0.y + s.y) + bb.y;
    e.z = (x0.z + s.z) + bb.z; e.w = (x0.w + s.w) + bb.w;
    *(float4*)&ws[OFF_ENC + (wg * 8 + r) * Dc + dg] = e;
    *(float4*)&encs[r][dg] = e;
  }
  __syncthreads();

  {
    const int f = tid & 255;
    const int rh = tid >> 8;
    float g[4];
    const float be1f = be1[f];
#pragma unroll
    for (int rr = 0; rr < 4; ++rr) g[rr] = be1f;
    for (int c = 0; c < Dc; ++c) {
      const float w = We1[c * Dc + f];
#pragma unroll
      for (int rr = 0; rr < 4; ++rr) g[rr] = fmaf(encs[rh * 4 + rr][c], w, g[rr]);
    }
    const float w2 = We2[f];
#pragma unroll
    for (int rr = 0; rr < 4; ++rr) {
      float p = fmaxf(g[rr], 0.f) * w2;
#pragma unroll
      for (int off = 32; off; off >>= 1) p += __shfl_down(p, off, 64);
      if (lane == 0) zred[wv][rr] = p;
    }
  }
  __syncthreads();
  if (tid < 8) {
    const int r = tid;
    const int wb = (r < 4) ? 0 : 4;
    const int rl = r & 3;
    const float z = ((zred[wb + 0][rl] + zred[wb + 1][rl]) + zred[wb + 2][rl]) +
                    zred[wb + 3][rl];
    ws[OFF_Z + wg * 8 + r] = z + be2[0];
  }
}

extern "C" void kernel_launch(void* const* d_in, const int* in_sizes, int n_in,
                              void* d_out, int out_size, void* d_ws, size_t ws_size,
                              hipStream_t stream) {
  const float* frames = (const float*)d_in[0];
  const float* cls    = (const float*)d_in[1];
  const float* Wq     = (const float*)d_in[2];
  const float* bq     = (const float*)d_in[3];
  const float* Wk     = (const float*)d_in[4];
  const float* bk     = (const float*)d_in[5];
  const float* Wv     = (const float*)d_in[6];
  const float* bv     = (const float*)d_in[7];
  const float* Wo     = (const float*)d_in[8];
  const float* bo     = (const float*)d_in[9];
  const float* g1     = (const float*)d_in[10];
  const float* b1     = (const float*)d_in[11];
  const float* g2     = (const float*)d_in[12];
  const float* b2     = (const float*)d_in[13];
  const float* W1     = (const float*)d_in[14];
  const float* b1f    = (const float*)d_in[15];
  const float* W2     = (const float*)d_in[16];
  const float* b2f    = (const float*)d_in[17];
  const float* We1    = (const float*)d_in[18];
  const float* be1    = (const float*)d_in[19];
  const float* We2    = (const float*)d_in[20];
  const float* be2    = (const float*)d_in[21];
  float* ws = (float*)d_ws;
  float* out = (float*)d_out;

  k_prep<<<Bc * Tc + 1, 256, 0, stream>>>(frames, cls, Wq, bq, Wk, bk, Wv, bv, Wo, g1, b1, ws);

  const size_t need = (size_t)(OFF_U + GSPLIT * NROWS * Dc) * sizeof(float);
  if (ws_size >= need) {
    k_fz<<<NT_FZ, 256, 0, stream>>>(cls, bo, g2, b2, W1, b1f, W2, ws);
    k_z<<<Bc * Tc, 512, 0, stream>>>(b2f, We1, be1, We2, be2, ws);
  } else {
    k_fused<<<Bc * Tc, 512, 0, stream>>>(cls, bo, g2, b2, W1, b1f, W2, b2f, We1, be1, We2, be2, ws);
  }
  k_emit<<<Bc, 256, 0, stream>>>(ws, out);
}